// Round 3
// baseline (205.526 us; speedup 1.0000x reference)
//
#include <hip/hip_runtime.h>
#include <hip/hip_bf16.h>
#include <math.h>

#define NN 8192      // nodes
#define NK 64        // clusters
#define EPSF 1e-6f
#define JSPLIT 16
#define JRANGE 512   // NN / JSPLIT
#define NCHUNK 16    // JRANGE / 32

typedef __attribute__((ext_vector_type(8))) short s16x8;
typedef __attribute__((ext_vector_type(4))) float f32x4;

static __device__ __forceinline__ short f2bf(float x) {
    union { float f; unsigned u; } v; v.f = x;
    unsigned r = (v.u + 0x7fffu + ((v.u >> 16) & 1u)) >> 16;
    return (short)r;
}

// ---------- pre-kernel: A [N][64] f32 -> AT [64][N] bf16 (LDS transpose) ----------
// 128 blocks x 256 threads; block handles 64 nodes x 64 k.
__global__ __launch_bounds__(256) void cvt_at(const float* __restrict__ A,
                                              unsigned short* __restrict__ AT) {
    __shared__ unsigned short T[64][72];   // [k][node], stride 144B (16B-aligned rows)
    int tid = threadIdx.x;
    int n0 = blockIdx.x * 64;
    int node = tid >> 2;            // 0..63
    int k4 = (tid & 3) << 4;        // 0,16,32,48
    const float* ap = A + (size_t)(n0 + node) * NK + k4;
    f32x4 x0 = *(const f32x4*)(ap);
    f32x4 x1 = *(const f32x4*)(ap + 4);
    f32x4 x2 = *(const f32x4*)(ap + 8);
    f32x4 x3 = *(const f32x4*)(ap + 12);
#pragma unroll
    for (int e = 0; e < 4; ++e) {
        T[k4 + e][node]      = (unsigned short)f2bf(x0[e]);
        T[k4 + 4 + e][node]  = (unsigned short)f2bf(x1[e]);
        T[k4 + 8 + e][node]  = (unsigned short)f2bf(x2[e]);
        T[k4 + 12 + e][node] = (unsigned short)f2bf(x3[e]);
    }
    __syncthreads();
    int k = tid >> 2;
    int seg = (tid & 3) << 4;       // 0,16,32,48
    s16x8 o0, o1;
#pragma unroll
    for (int e = 0; e < 8; ++e) { o0[e] = (short)T[k][seg + e]; o1[e] = (short)T[k][seg + 8 + e]; }
    unsigned short* dst = AT + (size_t)k * NN + n0 + seg;
    *(s16x8*)(dst)     = o0;
    *(s16x8*)(dst + 8) = o1;
}

// ---------- main fused pass over E ----------
// grid = 128 i-tiles * 16 j-splits = 2048 blocks (exactly 8/CU), 256 threads.
// Wave w owns rows i0+16w..+15; sweeps 16 32-col chunks with rotated start.
__global__ __launch_bounds__(256, 8) void pass_e(
    const float* __restrict__ E, const float* __restrict__ A,
    const unsigned short* __restrict__ AT,
    float* __restrict__ rowsum, float* __restrict__ colsum,
    float* __restrict__ within_part)
{
    __shared__ float csum[4][2][JRANGE];   // per-wave, even/odd-lane banks
    __shared__ float red[4];

    int tid = threadIdx.x;
    int w = tid >> 6, l = tid & 63;
    int bid = blockIdx.x;
    int itile = bid >> 4;      // 0..127
    int js = bid & 15;         // 0..15
    int i0 = itile * 64;
    int j0 = js * JRANGE;

    float* cf = &csum[0][0][0];
    for (int i = tid; i < 4 * 2 * JRANGE; i += 256) cf[i] = 0.f;
    __syncthreads();

    int lm = l & 15, lg = l >> 4;
    const float* erow = E + (size_t)(i0 + 16 * w + lm) * NN;
    const unsigned short* at0 = AT + (size_t)(lm +  0) * NN;
    const unsigned short* at1 = AT + (size_t)(lm + 16) * NN;
    const unsigned short* at2 = AT + (size_t)(lm + 32) * NN;
    const unsigned short* at3 = AT + (size_t)(lm + 48) * NN;

    int s0 = (itile + js * 5 + w * 9) & (NCHUNK - 1);

    f32x4 D0 = {0.f,0.f,0.f,0.f}, D1 = D0, D2 = D0, D3 = D0;
    float racc = 0.f;

    bool hi8 = (l & 8) != 0;
    bool hi4 = (l & 4) != 0;
    bool hi2 = (l & 2) != 0;
    int pofs = 8 * lg + ((l >> 1) & 7);    // column offset this lane deposits
    float* slot_base = &csum[w][l & 1][0];

    for (int t = 0; t < NCHUNK; ++t) {
        int jc = j0 + ((s0 + t) & (NCHUNK - 1)) * 32;
        int off = jc + 8 * lg;
        f32x4 va = *(const f32x4*)(erow + off);
        f32x4 vb = *(const f32x4*)(erow + off + 4);
        s16x8 b0 = *(const s16x8*)(at0 + off);
        s16x8 b1 = *(const s16x8*)(at1 + off);
        s16x8 b2 = *(const s16x8*)(at2 + off);
        s16x8 b3 = *(const s16x8*)(at3 + off);

        float v0 = va[0], v1 = va[1], v2 = va[2], v3 = va[3];
        float v4 = vb[0], v5 = vb[1], v6 = vb[2], v7 = vb[3];

        racc += ((v0 + v1) + (v2 + v3)) + ((v4 + v5) + (v6 + v7));

        // colsum halving reduce over the 16 lm-lanes: 7 shuffles total.
        // Round 1 (mask 8): keep cols (hi8?4-7:0-3), send the other half.
        float t0 = hi8 ? v0 : v4, t1 = hi8 ? v1 : v5;
        float t2 = hi8 ? v2 : v6, t3 = hi8 ? v3 : v7;
        t0 = __shfl_xor(t0, 8); t1 = __shfl_xor(t1, 8);
        t2 = __shfl_xor(t2, 8); t3 = __shfl_xor(t3, 8);
        float d0 = (hi8 ? v4 : v0) + t0;
        float d1 = (hi8 ? v5 : v1) + t1;
        float d2 = (hi8 ? v6 : v2) + t2;
        float d3 = (hi8 ? v7 : v3) + t3;
        // Round 2 (mask 4)
        float u0 = hi4 ? d0 : d2, u1 = hi4 ? d1 : d3;
        u0 = __shfl_xor(u0, 4); u1 = __shfl_xor(u1, 4);
        float e0 = (hi4 ? d2 : d0) + u0;
        float e1 = (hi4 ? d3 : d1) + u1;
        // Round 3 (mask 2)
        float q = hi2 ? e0 : e1;
        q = __shfl_xor(q, 2);
        float f = (hi2 ? e1 : e0) + q;
        // lanes l, l^1 hold complementary 8-lane partials of col (jc-j0)+pofs
        float* slot = slot_base + (jc - j0) + pofs;
        *slot += f;

        // bf16 A-fragment + 4 MFMAs (D[i][cluster] += E*A)
        s16x8 ef;
        ef[0]=f2bf(v0); ef[1]=f2bf(v1); ef[2]=f2bf(v2); ef[3]=f2bf(v3);
        ef[4]=f2bf(v4); ef[5]=f2bf(v5); ef[6]=f2bf(v6); ef[7]=f2bf(v7);
        D0 = __builtin_amdgcn_mfma_f32_16x16x32_bf16(ef, b0, D0, 0, 0, 0);
        D1 = __builtin_amdgcn_mfma_f32_16x16x32_bf16(ef, b1, D1, 0, 0, 0);
        D2 = __builtin_amdgcn_mfma_f32_16x16x32_bf16(ef, b2, D2, 0, 0, 0);
        D3 = __builtin_amdgcn_mfma_f32_16x16x32_bf16(ef, b3, D3, 0, 0, 0);
    }

    // rowsum: sum the 4 lg-lanes sharing a row
    racc += __shfl_xor(racc, 16);
    racc += __shfl_xor(racc, 32);
    if (l < 16) atomicAdd(&rowsum[i0 + 16 * w + l], racc);

    // within partial: sum_{i,k} D[i][k] * A_f32[i][k]
    float wsum = 0.f;
    const float* Ab = A + (size_t)(i0 + 16 * w + 4 * lg) * NK + lm;
#pragma unroll
    for (int r = 0; r < 4; ++r) {
        const float* ar = Ab + (size_t)r * NK;
        wsum += D0[r] * ar[0];
        wsum += D1[r] * ar[16];
        wsum += D2[r] * ar[32];
        wsum += D3[r] * ar[48];
    }
#pragma unroll
    for (int m = 1; m < 64; m <<= 1) wsum += __shfl_xor(wsum, m);
    if (l == 0) red[w] = wsum;
    __syncthreads();

    if (tid == 0) within_part[bid] = red[0] + red[1] + red[2] + red[3];
    for (int c = tid; c < JRANGE; c += 256) {
        float s = (csum[0][0][c] + csum[0][1][c]) + (csum[1][0][c] + csum[1][1][c])
                + (csum[2][0][c] + csum[2][1][c]) + (csum[3][0][c] + csum[3][1][c]);
        atomicAdd(&colsum[j0 + c], s);
    }
}

// ---------- spatial pass 1: argmax ids + counts + coord sums ----------
__global__ __launch_bounds__(256) void spatial1(
    const float* __restrict__ A, const float* __restrict__ pos,
    int* __restrict__ ids, float* __restrict__ counts, float* __restrict__ sums)
{
    int wv = threadIdx.x >> 6, l = threadIdx.x & 63;
    int node = blockIdx.x * 4 + wv;
    float v = A[(size_t)node * NK + l];
    int idx = l;
#pragma unroll
    for (int m = 1; m < 64; m <<= 1) {
        float ov = __shfl_xor(v, m);
        int oi = __shfl_xor(idx, m);
        if (ov > v || (ov == v && oi < idx)) { v = ov; idx = oi; }
    }
    if (l == 0) {
        ids[node] = idx;
        atomicAdd(&counts[idx], 1.0f);
        atomicAdd(&sums[idx * 2 + 0], pos[(size_t)node * 2 + 0]);
        atomicAdd(&sums[idx * 2 + 1], pos[(size_t)node * 2 + 1]);
    }
}

// ---------- spatial pass 2: distances to centroids ----------
__global__ __launch_bounds__(256) void spatial2(
    const int* __restrict__ ids, const float* __restrict__ pos,
    const float* __restrict__ counts, const float* __restrict__ sums,
    float* __restrict__ distsum, int* __restrict__ maxid)
{
    __shared__ float ds[64];
    __shared__ int mx;
    int tid = threadIdx.x;
    if (tid < 64) ds[tid] = 0.f;
    if (tid == 0) mx = 0;
    __syncthreads();
    int i = blockIdx.x * 256 + tid;
    int id = ids[i];
    float den = counts[id] + EPSF;
    float cx = sums[id * 2 + 0] / den;
    float cy = sums[id * 2 + 1] / den;
    float dx = pos[(size_t)i * 2 + 0] - cx;
    float dy = pos[(size_t)i * 2 + 1] - cy;
    atomicAdd(&ds[id], sqrtf(dx * dx + dy * dy));
    atomicMax(&mx, id);
    __syncthreads();
    if (tid < 64) atomicAdd(&distsum[tid], ds[tid]);
    if (tid == 0) atomicMax(maxid, mx);
}

// ---------- finalize ----------
__global__ __launch_bounds__(256) void finalize(
    const float* __restrict__ rowsum, const float* __restrict__ colsum,
    const float* __restrict__ cons, const float* __restrict__ gen,
    const float* __restrict__ within_part, const float* __restrict__ counts,
    const float* __restrict__ distsum, const int* __restrict__ maxid,
    float* __restrict__ out)
{
    __shared__ float redb[4], rede[4], redw[4];
    int tid = threadIdx.x;
    int w = tid >> 6, l = tid & 63;
    float bacc = 0.f, eacc = 0.f, wacc = 0.f;
    for (int i = tid; i < NN; i += 256) {
        float imb = (cons[i] - gen[i]) - (colsum[i] - rowsum[i]);
        bacc += imb * imb;
        eacc += rowsum[i];
    }
    for (int i = tid; i < 2048; i += 256) wacc += within_part[i];
#pragma unroll
    for (int m = 1; m < 64; m <<= 1) {
        bacc += __shfl_xor(bacc, m);
        eacc += __shfl_xor(eacc, m);
        wacc += __shfl_xor(wacc, m);
    }
    if (l == 0) { redb[w] = bacc; rede[w] = eacc; redw[w] = wacc; }
    __syncthreads();

    float sacc = 0.f;
    if (tid < 64) {
        float c = counts[tid];
        float avg = distsum[tid] / (c + EPSF);
        sacc = (c >= 2.0f) ? avg : 0.f;
#pragma unroll
        for (int m = 1; m < 64; m <<= 1) sacc += __shfl_xor(sacc, m);
    }
    if (tid == 0) {
        float balance = (redb[0] + redb[1] + redb[2] + redb[3]) / (float)NN;
        float sumE = rede[0] + rede[1] + rede[2] + rede[3];
        float W = redw[0] + redw[1] + redw[2] + redw[3];
        float clustering = (sumE - 2.0f * W) / ((float)NN * (float)NN + EPSF);
        float nc = (float)(maxid[0] + 1) + EPSF;
        float spatial = sacc / nc;
        float total = 1.0f * balance + 0.5f * spatial + 0.3f * clustering;
        out[0] = total;
        out[1] = balance;
        out[2] = spatial;
        out[3] = clustering;
    }
}

extern "C" void kernel_launch(void* const* d_in, const int* in_sizes, int n_in,
                              void* d_out, int out_size, void* d_ws, size_t ws_size,
                              hipStream_t stream) {
    const float* E    = (const float*)d_in[0];
    const float* A    = (const float*)d_in[1];
    const float* pos  = (const float*)d_in[2];
    const float* cons = (const float*)d_in[3];
    const float* gen  = (const float*)d_in[4];
    float* out = (float*)d_out;

    char* ws = (char*)d_ws;
    unsigned short* AT = (unsigned short*)ws;                 // 64*N bf16 = 1 MB
    float* rowsum      = (float*)(ws + (size_t)2 * NK * NN);  // [N]
    float* colsum      = rowsum + NN;                         // [N]
    float* counts      = colsum + NN;                         // [64]
    float* sums        = counts + 64;                         // [64][2]
    float* distsum     = sums + 128;                          // [64]
    int*   maxid       = (int*)(distsum + 64);                // [1]
    float* within_part = (float*)(maxid + 1);                 // [2048]
    int*   ids         = (int*)(within_part + 2048);          // [N]

    size_t zbytes = ((size_t)NN * 2 + 64 + 128 + 64 + 1) * 4;
    hipMemsetAsync(rowsum, 0, zbytes, stream);

    cvt_at  <<<NN / 64, 256, 0, stream>>>(A, AT);
    pass_e  <<<(NN / 64) * JSPLIT, 256, 0, stream>>>(E, A, AT, rowsum, colsum, within_part);
    spatial1<<<NN / 4, 256, 0, stream>>>(A, pos, ids, counts, sums);
    spatial2<<<NN / 256, 256, 0, stream>>>(ids, pos, counts, sums, distsum, maxid);
    finalize<<<1, 256, 0, stream>>>(rowsum, colsum, cons, gen, within_part, counts, distsum, maxid, out);
}

// Round 4
// 146.661 us; speedup vs baseline: 1.4014x; 1.4014x over previous
//
#include <hip/hip_runtime.h>
#include <hip/hip_bf16.h>
#include <math.h>

#define NN 8192      // nodes
#define NK 64        // clusters
#define EPSF 1e-6f
#define JW 256       // cols per block (j-window)
#define TM 64        // rows per tile
#define NTILE 4      // tiles per block -> 256 rows per block
// grid: 32 j-strips x 32 i-groups = 1024 blocks, 256 threads (4 waves)

typedef __attribute__((ext_vector_type(8))) short s16x8;
typedef __attribute__((ext_vector_type(4))) short s16x4;
typedef __attribute__((ext_vector_type(4))) float f32x4;

static __device__ __forceinline__ short f2bf(float x) {
    union { float f; unsigned u; } v; v.f = x;
    unsigned r = (v.u + 0x7fffu + ((v.u >> 16) & 1u)) >> 16;
    return (short)r;
}

// ---------- pre-kernel: A [N][64] f32 -> AT [64][N] bf16 (LDS transpose) ----------
__global__ __launch_bounds__(256) void cvt_at(const float* __restrict__ A,
                                              unsigned short* __restrict__ AT) {
    __shared__ unsigned short T[64][72];
    int tid = threadIdx.x;
    int n0 = blockIdx.x * 64;
    int node = tid >> 2;
    int k4 = (tid & 3) << 4;
    const float* ap = A + (size_t)(n0 + node) * NK + k4;
    f32x4 x0 = *(const f32x4*)(ap);
    f32x4 x1 = *(const f32x4*)(ap + 4);
    f32x4 x2 = *(const f32x4*)(ap + 8);
    f32x4 x3 = *(const f32x4*)(ap + 12);
#pragma unroll
    for (int e = 0; e < 4; ++e) {
        T[k4 + e][node]      = (unsigned short)f2bf(x0[e]);
        T[k4 + 4 + e][node]  = (unsigned short)f2bf(x1[e]);
        T[k4 + 8 + e][node]  = (unsigned short)f2bf(x2[e]);
        T[k4 + 12 + e][node] = (unsigned short)f2bf(x3[e]);
    }
    __syncthreads();
    int k = tid >> 2;
    int seg = (tid & 3) << 4;
    s16x8 o0, o1;
#pragma unroll
    for (int e = 0; e < 8; ++e) { o0[e] = (short)T[k][seg + e]; o1[e] = (short)T[k][seg + 8 + e]; }
    unsigned short* dst = AT + (size_t)k * NN + n0 + seg;
    *(s16x8*)(dst)     = o0;
    *(s16x8*)(dst + 8) = o1;
}

// ---------- main fused pass over E: contiguous 1KB-per-instruction loads ----------
__global__ __launch_bounds__(256) void pass_e(
    const float* __restrict__ E, const float* __restrict__ A,
    const unsigned short* __restrict__ AT,
    float* __restrict__ rowsum, float* __restrict__ colsum,
    float* __restrict__ within_part)
{
    __shared__ unsigned short Ebf[TM * JW];   // 32KB, swizzled rows of 512B
    __shared__ unsigned short ATl[NK * JW];   // 32KB, swizzled rows of 512B
    __shared__ float csum[4][JW];             // 4KB
    __shared__ float red[4];

    int tid = threadIdx.x;
    int w = tid >> 6, l = tid & 63;
    int bid = blockIdx.x;
    int jstrip = bid & 31;
    int ig = bid >> 5;
    int jbase = jstrip * JW;
    int ibase = ig * (TM * NTILE);
    int lm = l & 15, lg = l >> 4;

    // ---- stage AT strip: 64 clusters x 256 cols bf16, swizzled ----
    {
        int l5 = l >> 5, c32 = l & 31;
#pragma unroll
        for (int q = 0; q < 8; ++q) {
            int cl = 16 * w + 2 * q + l5;
            s16x8 v = *(const s16x8*)(AT + (size_t)cl * NN + jbase + c32 * 8);
            *(s16x8*)((char*)ATl + cl * 512 + ((c32 * 16) ^ ((cl & 7) << 4))) = v;
        }
    }

    float creg0 = 0.f, creg1 = 0.f, creg2 = 0.f, creg3 = 0.f;
    float wsum = 0.f;
    s16x8 ONES;
#pragma unroll
    for (int e = 0; e < 8; ++e) ONES[e] = (short)0x3F80;  // bf16 1.0

    for (int t = 0; t < NTILE; ++t) {
        int r0 = ibase + TM * t;
        // ---- load 16 rows (one full-row 1KB instruction each), colsum in reg, bf16 to LDS ----
#pragma unroll
        for (int q = 0; q < 16; ++q) {
            int rr = 16 * w + q;
            f32x4 v = *(const f32x4*)(E + (size_t)(r0 + rr) * NN + jbase + l * 4);
            creg0 += v[0]; creg1 += v[1]; creg2 += v[2]; creg3 += v[3];
            s16x4 b;
            b[0] = f2bf(v[0]); b[1] = f2bf(v[1]); b[2] = f2bf(v[2]); b[3] = f2bf(v[3]);
            *(s16x4*)((char*)Ebf + rr * 512 + ((l * 8) ^ ((rr & 7) << 4))) = b;
        }
        __syncthreads();   // Ebf (and, first iter, ATl) ready

        // ---- MFMA phase: 8 k-chunks x (4 within + 1 rowsum) ----
        f32x4 D0 = {0.f,0.f,0.f,0.f}, D1 = D0, D2 = D0, D3 = D0, Dr = D0;
#pragma unroll
        for (int kc = 0; kc < 8; ++kc) {
            int inner = (kc * 64 + lg * 16) ^ ((lm & 7) << 4);
            s16x8 ef = *(const s16x8*)((char*)Ebf + lm * 512 + inner);
            s16x8 a0 = *(const s16x8*)((char*)ATl + (lm +  0) * 512 + inner);
            s16x8 a1 = *(const s16x8*)((char*)ATl + (lm + 16) * 512 + inner);
            s16x8 a2 = *(const s16x8*)((char*)ATl + (lm + 32) * 512 + inner);
            s16x8 a3 = *(const s16x8*)((char*)ATl + (lm + 48) * 512 + inner);
            D0 = __builtin_amdgcn_mfma_f32_16x16x32_bf16(ef, a0, D0, 0, 0, 0);
            D1 = __builtin_amdgcn_mfma_f32_16x16x32_bf16(ef, a1, D1, 0, 0, 0);
            D2 = __builtin_amdgcn_mfma_f32_16x16x32_bf16(ef, a2, D2, 0, 0, 0);
            D3 = __builtin_amdgcn_mfma_f32_16x16x32_bf16(ef, a3, D3, 0, 0, 0);
            Dr = __builtin_amdgcn_mfma_f32_16x16x32_bf16(ef, ONES, Dr, 0, 0, 0);
        }
        __syncthreads();   // done reading Ebf before next tile overwrites

        // ---- per-tile epilogue (registers + global only) ----
        if (lm == 0) {
#pragma unroll
            for (int r = 0; r < 4; ++r)
                atomicAdd(&rowsum[r0 + 16 * w + 4 * lg + r], Dr[r]);
        }
        const float* Ab = A + (size_t)(r0 + 16 * w + 4 * lg) * NK + lm;
#pragma unroll
        for (int r = 0; r < 4; ++r) {
            const float* ar = Ab + (size_t)r * NK;
            wsum += D0[r] * ar[0] + D1[r] * ar[16] + D2[r] * ar[32] + D3[r] * ar[48];
        }
    }

    // ---- block epilogue: colsum combine + within reduce ----
    f32x4 cv = { creg0, creg1, creg2, creg3 };
    *(f32x4*)&csum[w][l * 4] = cv;
#pragma unroll
    for (int m = 1; m < 64; m <<= 1) wsum += __shfl_xor(wsum, m);
    if (l == 0) red[w] = wsum;
    __syncthreads();

    {
        int c = tid;  // 256 threads, 256 cols
        float s = (csum[0][c] + csum[1][c]) + (csum[2][c] + csum[3][c]);
        atomicAdd(&colsum[jbase + c], s);
    }
    if (tid == 0) within_part[bid] = red[0] + red[1] + red[2] + red[3];
}

// ---------- spatial pass 1: argmax ids + counts + coord sums ----------
__global__ __launch_bounds__(256) void spatial1(
    const float* __restrict__ A, const float* __restrict__ pos,
    int* __restrict__ ids, float* __restrict__ counts, float* __restrict__ sums)
{
    int wv = threadIdx.x >> 6, l = threadIdx.x & 63;
    int node = blockIdx.x * 4 + wv;
    float v = A[(size_t)node * NK + l];
    int idx = l;
#pragma unroll
    for (int m = 1; m < 64; m <<= 1) {
        float ov = __shfl_xor(v, m);
        int oi = __shfl_xor(idx, m);
        if (ov > v || (ov == v && oi < idx)) { v = ov; idx = oi; }
    }
    if (l == 0) {
        ids[node] = idx;
        atomicAdd(&counts[idx], 1.0f);
        atomicAdd(&sums[idx * 2 + 0], pos[(size_t)node * 2 + 0]);
        atomicAdd(&sums[idx * 2 + 1], pos[(size_t)node * 2 + 1]);
    }
}

// ---------- spatial pass 2: distances to centroids ----------
__global__ __launch_bounds__(256) void spatial2(
    const int* __restrict__ ids, const float* __restrict__ pos,
    const float* __restrict__ counts, const float* __restrict__ sums,
    float* __restrict__ distsum, int* __restrict__ maxid)
{
    __shared__ float ds[64];
    __shared__ int mx;
    int tid = threadIdx.x;
    if (tid < 64) ds[tid] = 0.f;
    if (tid == 0) mx = 0;
    __syncthreads();
    int i = blockIdx.x * 256 + tid;
    int id = ids[i];
    float den = counts[id] + EPSF;
    float cx = sums[id * 2 + 0] / den;
    float cy = sums[id * 2 + 1] / den;
    float dx = pos[(size_t)i * 2 + 0] - cx;
    float dy = pos[(size_t)i * 2 + 1] - cy;
    atomicAdd(&ds[id], sqrtf(dx * dx + dy * dy));
    atomicMax(&mx, id);
    __syncthreads();
    if (tid < 64) atomicAdd(&distsum[tid], ds[tid]);
    if (tid == 0) atomicMax(maxid, mx);
}

// ---------- finalize ----------
__global__ __launch_bounds__(256) void finalize(
    const float* __restrict__ rowsum, const float* __restrict__ colsum,
    const float* __restrict__ cons, const float* __restrict__ gen,
    const float* __restrict__ within_part, const float* __restrict__ counts,
    const float* __restrict__ distsum, const int* __restrict__ maxid,
    float* __restrict__ out)
{
    __shared__ float redb[4], rede[4], redw[4];
    int tid = threadIdx.x;
    int w = tid >> 6, l = tid & 63;
    float bacc = 0.f, eacc = 0.f, wacc = 0.f;
    for (int i = tid; i < NN; i += 256) {
        float imb = (cons[i] - gen[i]) - (colsum[i] - rowsum[i]);
        bacc += imb * imb;
        eacc += rowsum[i];
    }
    for (int i = tid; i < 1024; i += 256) wacc += within_part[i];
#pragma unroll
    for (int m = 1; m < 64; m <<= 1) {
        bacc += __shfl_xor(bacc, m);
        eacc += __shfl_xor(eacc, m);
        wacc += __shfl_xor(wacc, m);
    }
    if (l == 0) { redb[w] = bacc; rede[w] = eacc; redw[w] = wacc; }
    __syncthreads();

    float sacc = 0.f;
    if (tid < 64) {
        float c = counts[tid];
        float avg = distsum[tid] / (c + EPSF);
        sacc = (c >= 2.0f) ? avg : 0.f;
#pragma unroll
        for (int m = 1; m < 64; m <<= 1) sacc += __shfl_xor(sacc, m);
    }
    if (tid == 0) {
        float balance = (redb[0] + redb[1] + redb[2] + redb[3]) / (float)NN;
        float sumE = rede[0] + rede[1] + rede[2] + rede[3];
        float W = redw[0] + redw[1] + redw[2] + redw[3];
        float clustering = (sumE - 2.0f * W) / ((float)NN * (float)NN + EPSF);
        float nc = (float)(maxid[0] + 1) + EPSF;
        float spatial = sacc / nc;
        float total = 1.0f * balance + 0.5f * spatial + 0.3f * clustering;
        out[0] = total;
        out[1] = balance;
        out[2] = spatial;
        out[3] = clustering;
    }
}

extern "C" void kernel_launch(void* const* d_in, const int* in_sizes, int n_in,
                              void* d_out, int out_size, void* d_ws, size_t ws_size,
                              hipStream_t stream) {
    const float* E    = (const float*)d_in[0];
    const float* A    = (const float*)d_in[1];
    const float* pos  = (const float*)d_in[2];
    const float* cons = (const float*)d_in[3];
    const float* gen  = (const float*)d_in[4];
    float* out = (float*)d_out;

    char* ws = (char*)d_ws;
    unsigned short* AT = (unsigned short*)ws;                 // 64*N bf16 = 1 MB
    float* rowsum      = (float*)(ws + (size_t)2 * NK * NN);  // [N]
    float* colsum      = rowsum + NN;                         // [N]
    float* counts      = colsum + NN;                         // [64]
    float* sums        = counts + 64;                         // [64][2]
    float* distsum     = sums + 128;                          // [64]
    int*   maxid       = (int*)(distsum + 64);                // [1]
    float* within_part = (float*)(maxid + 1);                 // [1024]
    int*   ids         = (int*)(within_part + 1024);          // [N]

    size_t zbytes = ((size_t)NN * 2 + 64 + 128 + 64 + 1) * 4;
    hipMemsetAsync(rowsum, 0, zbytes, stream);

    cvt_at  <<<NN / 64, 256, 0, stream>>>(A, AT);
    pass_e  <<<32 * 32, 256, 0, stream>>>(E, A, AT, rowsum, colsum, within_part);
    spatial1<<<NN / 4, 256, 0, stream>>>(A, pos, ids, counts, sums);
    spatial2<<<NN / 256, 256, 0, stream>>>(ids, pos, counts, sums, distsum, maxid);
    finalize<<<1, 256, 0, stream>>>(rowsum, colsum, cons, gen, within_part, counts, distsum, maxid, out);
}